// Round 9
// baseline (213.831 us; speedup 1.0000x reference)
//
#include <hip/hip_runtime.h>
#include <hip/hip_fp16.h>

#define N_NODES 50000
#define EMB 128
#define HID 64
#define NR 16
#define NC 16
#define NE 800000
#define J1 (NR*HID + HID)   /* 1088 = 17*64 */
#define J2 (NR*NC + NC)     /* 272  = 17*16 */
#define NSL 4               /* bucket slices (XCD pairs) */
#define CAPS 20             /* capacity per (dst, slice): deg/slice ~ Poisson(4) */

typedef _Float16 f16;
typedef __attribute__((ext_vector_type(8))) _Float16 f16x8;
typedef __attribute__((ext_vector_type(4))) _Float16 f16x4;
typedef __attribute__((ext_vector_type(4))) float f32x4;

// ---- build packed transposed fp16 B: Bt1[1088][128], Bt2[272][64] ----------
__global__ __launch_bounds__(256)
void k_bb(const float* __restrict__ W1, const float* __restrict__ root1,
          const float* __restrict__ W2, const float* __restrict__ root2,
          f16* __restrict__ Bt1, f16* __restrict__ Bt2) {
    int idx = blockIdx.x * 256 + threadIdx.x;
    const int total1 = J1 * EMB;   // 139264
    const int total2 = J2 * HID;   // 17408
    if (idx < total1) {
        int j = idx / EMB, i = idx % EMB;
        float v = (j < NR*HID) ? W1[((size_t)(j >> 6) * EMB + i) * HID + (j & 63)]
                               : root1[i * HID + (j - NR*HID)];
        Bt1[idx] = (f16)v;
    } else if (idx < total1 + total2) {
        int t = idx - total1;
        int j = t / HID, i = t % HID;
        float v = (j < NR*NC) ? W2[((size_t)(j >> 4) * HID + i) * NC + (j & 15)]
                              : root2[i * NC + (j - NR*NC)];
        Bt2[t] = (f16)v;
    }
}

// ---- XCD-sliced edge scatter ------------------------------------------------
// slice = XCC_ID>>1: each XCD-pair writes ONLY its private cur/packed slice ->
// counter lines 4x less loaded, bucket lines single-slice (no cross-XCD dirty
// sharing). entry = src*17 + type (Y1 row / 64).
__global__ __launch_bounds__(256)
void k_scat(const int* __restrict__ ei, const int* __restrict__ et,
            int* __restrict__ cur4, unsigned* __restrict__ packed4) {
    int e = blockIdx.x * 256 + threadIdx.x;
    if (e >= NE) return;
    unsigned x;
    asm volatile("s_getreg_b32 %0, hwreg(HW_REG_XCC_ID)" : "=s"(x));
    int sl = (int)((x >> 1) & 3);
    int s = ei[e], d = ei[NE + e], t = et[e];
    int cell = sl * N_NODES + d;
    int pos = atomicAdd(&cur4[cell], 1);
    if (pos < CAPS)
        packed4[(size_t)cell * CAPS + pos] = (unsigned)(s * 17 + t);
}

// ---- GEMM1: Y1[N,J1] = emb(f32->f16) @ Bt1^T --------------------------------
__global__ __launch_bounds__(512)
void k_gemm1(const float* __restrict__ A, const f16* __restrict__ Bt,
             f16* __restrict__ C) {
    constexpr int K = EMB, KP = K + 8;
    __shared__ f16 As[128 * KP];
    __shared__ f16 Bs[128 * KP];
    int tid = threadIdx.x;
    int m0 = blockIdx.y * 128, n0 = blockIdx.x * 128;

    for (int idx = tid; idx < 128 * 32; idx += 512) {     // A: f32 load, cvt f16
        int r = idx >> 5, c = idx & 31;
        float4 v = make_float4(0.f, 0.f, 0.f, 0.f);
        if (m0 + r < N_NODES) v = reinterpret_cast<const float4*>(A)[(size_t)(m0 + r) * 32 + c];
        f16x4 h = {(f16)v.x, (f16)v.y, (f16)v.z, (f16)v.w};
        *reinterpret_cast<f16x4*>(&As[r * KP + c * 4]) = h;
    }
    for (int idx = tid; idx < 128 * 16; idx += 512) {     // B: f16x8
        int r = idx >> 4, c = idx & 15;
        f16x8 vb = {};
        if (n0 + r < J1) vb = *reinterpret_cast<const f16x8*>(Bt + (size_t)(n0 + r) * K + c * 8);
        *reinterpret_cast<f16x8*>(&Bs[r * KP + c * 8]) = vb;
    }
    __syncthreads();

    int w = tid >> 6, lane = tid & 63;
    int wr = (w >> 2) * 64, wc = (w & 3) * 32;
    int lr = lane & 15, lk = (lane >> 4) * 8;

    f32x4 acc[4][2];
#pragma unroll
    for (int mm = 0; mm < 4; mm++)
#pragma unroll
        for (int nn = 0; nn < 2; nn++) acc[mm][nn] = (f32x4){0.f, 0.f, 0.f, 0.f};

#pragma unroll
    for (int k0 = 0; k0 < K; k0 += 32) {
        f16x8 a[4], b[2];
#pragma unroll
        for (int mm = 0; mm < 4; mm++)
            a[mm] = *reinterpret_cast<const f16x8*>(&As[(wr + mm*16 + lr) * KP + k0 + lk]);
#pragma unroll
        for (int nn = 0; nn < 2; nn++)
            b[nn] = *reinterpret_cast<const f16x8*>(&Bs[(wc + nn*16 + lr) * KP + k0 + lk]);
#pragma unroll
        for (int mm = 0; mm < 4; mm++)
#pragma unroll
            for (int nn = 0; nn < 2; nn++)
                acc[mm][nn] = __builtin_amdgcn_mfma_f32_16x16x32_f16(a[mm], b[nn], acc[mm][nn], 0, 0, 0);
    }

    int g = lane >> 4;
#pragma unroll
    for (int mm = 0; mm < 4; mm++)
#pragma unroll
        for (int nn = 0; nn < 2; nn++) {
            int col = n0 + wc + nn*16 + lr;
            if (col < J1) {
#pragma unroll
                for (int q = 0; q < 4; q++) {
                    int row = m0 + wr + mm*16 + g*4 + q;
                    if (row < N_NODES) C[(size_t)row * J1 + col] = (f16)acc[mm][nn][q];
                }
            }
        }
}

// ---- MFMA GEMM for layer 2 (f16 A) ------------------------------------------
template<int K, typename OutT>
__global__ __launch_bounds__(512)
void k_mfma(const f16* __restrict__ A, const f16* __restrict__ Bt,
            OutT* __restrict__ C, int N, int J) {
    constexpr int KP = K + 8;
    __shared__ f16 As[128 * KP];
    __shared__ f16 Bs[128 * KP];
    int tid = threadIdx.x;
    int m0 = blockIdx.y * 128, n0 = blockIdx.x * 128;

    constexpr int V = K / 8;
    for (int idx = tid; idx < 128 * V; idx += 512) {
        int r = idx / V, c = idx % V;
        f16x8 va = {}, vb = {};
        if (m0 + r < N) va = *reinterpret_cast<const f16x8*>(A + (size_t)(m0 + r) * K + c * 8);
        if (n0 + r < J) vb = *reinterpret_cast<const f16x8*>(Bt + (size_t)(n0 + r) * K + c * 8);
        *reinterpret_cast<f16x8*>(&As[r * KP + c * 8]) = va;
        *reinterpret_cast<f16x8*>(&Bs[r * KP + c * 8]) = vb;
    }
    __syncthreads();

    int w = tid >> 6, lane = tid & 63;
    int wr = (w >> 2) * 64, wc = (w & 3) * 32;
    int lr = lane & 15, lk = (lane >> 4) * 8;

    f32x4 acc[4][2];
#pragma unroll
    for (int mm = 0; mm < 4; mm++)
#pragma unroll
        for (int nn = 0; nn < 2; nn++) acc[mm][nn] = (f32x4){0.f, 0.f, 0.f, 0.f};

#pragma unroll
    for (int k0 = 0; k0 < K; k0 += 32) {
        f16x8 a[4], b[2];
#pragma unroll
        for (int mm = 0; mm < 4; mm++)
            a[mm] = *reinterpret_cast<const f16x8*>(&As[(wr + mm*16 + lr) * KP + k0 + lk]);
#pragma unroll
        for (int nn = 0; nn < 2; nn++)
            b[nn] = *reinterpret_cast<const f16x8*>(&Bs[(wc + nn*16 + lr) * KP + k0 + lk]);
#pragma unroll
        for (int mm = 0; mm < 4; mm++)
#pragma unroll
            for (int nn = 0; nn < 2; nn++)
                acc[mm][nn] = __builtin_amdgcn_mfma_f32_16x16x32_f16(a[mm], b[nn], acc[mm][nn], 0, 0, 0);
    }

    int g = lane >> 4;
#pragma unroll
    for (int mm = 0; mm < 4; mm++)
#pragma unroll
        for (int nn = 0; nn < 2; nn++) {
            int col = n0 + wc + nn*16 + lr;
            if (col < J) {
#pragma unroll
                for (int q = 0; q < 4; q++) {
                    int row = m0 + wr + mm*16 + g*4 + q;
                    if (row < N) C[(size_t)row * J + col] = (OutT)acc[mm][nn][q];
                }
            }
        }
}

// ---- slice-compaction prologue (shared by agg kernels) ----------------------
// 4 waves/block, wave per node. Concatenates the node's 4 bucket slices into
// LDS, returns deg (clamped 64) and this lane's compacted entry.
__device__ __forceinline__ unsigned compact_entries(
        const int* __restrict__ cur4, const unsigned* __restrict__ packed4,
        int n, int lane, int wv, unsigned (*lds_e)[NSL * CAPS], int& deg_out) {
    int off = 0, deg = 0, myc = 0;
    int s = lane >> 4, p = lane & 15;          // 16 lanes per slice
#pragma unroll
    for (int q = 0; q < NSL; q++) {
        int c = cur4[q * N_NODES + n]; c = c > CAPS ? CAPS : c;
        if (q < s) off += c;
        if (q == s) myc = c;
        deg += c;
    }
    const unsigned* base = packed4 + (size_t)(s * N_NODES + n) * CAPS;
    if (p < myc)      lds_e[wv][off + p] = base[p];
    if (p + 16 < myc) lds_e[wv][off + p + 16] = base[p + 16];
    __syncthreads();
    deg_out = deg > 64 ? 64 : deg;
    return lds_e[wv][lane];
}

// ---- fused layer-1 aggregation + finalize ------------------------------------
__global__ __launch_bounds__(256)
void k_agg1f(const int* __restrict__ cur4, const unsigned* __restrict__ packed4,
             const f16* __restrict__ Y1, const float* __restrict__ b1,
             f16* __restrict__ X1h) {
    __shared__ unsigned lds_e[4][NSL * CAPS];
    int n = (blockIdx.x * 256 + threadIdx.x) >> 6;     // grid exact: no early exit
    int lane = threadIdx.x & 63, wv = (threadIdx.x >> 6) & 3;
    int deg;
    unsigned my = compact_entries(cur4, packed4, n, lane, wv, lds_e, deg);
    int tp = (int)(my % 17u);
    float wreg = 0.f;
#pragma unroll
    for (int r = 0; r < 16; r++) {
        unsigned long long b = __ballot(lane < deg && tp == r);
        if (lane == r) wreg = 1.0f / fmaxf((float)__popcll(b), 1.0f);
    }
    float w_my = __shfl(wreg, tp);
    int c4 = lane & 15, grp = lane >> 4;
    const f16* Yb = Y1 + c4 * 4;
    float a0 = 0.f, a1 = 0.f, a2 = 0.f, a3 = 0.f;
    for (int i = 0; i < deg; i += 4) {
        int idx = i + grp;
        unsigned en = __shfl(my, idx);
        float we = __shfl(w_my, idx);
        if (idx < deg) {
            f16x4 v = *reinterpret_cast<const f16x4*>(Yb + ((size_t)en << 6));
            a0 += we * (float)v[0]; a1 += we * (float)v[1];
            a2 += we * (float)v[2]; a3 += we * (float)v[3];
        }
    }
    a0 += __shfl_xor(a0, 16); a0 += __shfl_xor(a0, 32);
    a1 += __shfl_xor(a1, 16); a1 += __shfl_xor(a1, 32);
    a2 += __shfl_xor(a2, 16); a2 += __shfl_xor(a2, 32);
    a3 += __shfl_xor(a3, 16); a3 += __shfl_xor(a3, 32);
    if (grp == 0) {
        f16x4 rt = *reinterpret_cast<const f16x4*>(Y1 + ((size_t)n * 17 + 16) * 64 + c4 * 4);
        float4 bb = *reinterpret_cast<const float4*>(b1 + c4 * 4);
        f16x4 o = {(f16)fmaxf(a0 + (float)rt[0] + bb.x, 0.f),
                   (f16)fmaxf(a1 + (float)rt[1] + bb.y, 0.f),
                   (f16)fmaxf(a2 + (float)rt[2] + bb.z, 0.f),
                   (f16)fmaxf(a3 + (float)rt[3] + bb.w, 0.f)};
        *reinterpret_cast<f16x4*>(X1h + (size_t)n * HID + c4 * 4) = o;
    }
}

// ---- fused layer-2 aggregation + finalize ------------------------------------
__global__ __launch_bounds__(256)
void k_agg2f(const int* __restrict__ cur4, const unsigned* __restrict__ packed4,
             const float* __restrict__ Y2, const float* __restrict__ b2,
             float* __restrict__ out) {
    __shared__ unsigned lds_e[4][NSL * CAPS];
    int n = (blockIdx.x * 256 + threadIdx.x) >> 6;
    int lane = threadIdx.x & 63, wv = (threadIdx.x >> 6) & 3;
    int deg;
    unsigned my = compact_entries(cur4, packed4, n, lane, wv, lds_e, deg);
    int tp = (int)(my % 17u);
    float wreg = 0.f;
#pragma unroll
    for (int r = 0; r < 16; r++) {
        unsigned long long b = __ballot(lane < deg && tp == r);
        if (lane == r) wreg = 1.0f / fmaxf((float)__popcll(b), 1.0f);
    }
    float w_my = __shfl(wreg, tp);
    int c4 = lane & 3, grp = lane >> 2;             // 16 groups x 4 quads
    const float* Yb = Y2 + c4 * 4;
    float a0 = 0.f, a1 = 0.f, a2 = 0.f, a3 = 0.f;
    for (int i = 0; i < deg; i += 16) {
        int idx = i + grp;
        unsigned en = __shfl(my, idx);
        float we = __shfl(w_my, idx);
        if (idx < deg) {
            float4 v = *reinterpret_cast<const float4*>(Yb + ((size_t)en << 4));
            a0 += we * v.x; a1 += we * v.y; a2 += we * v.z; a3 += we * v.w;
        }
    }
#pragma unroll
    for (int sh = 4; sh <= 32; sh <<= 1) {
        a0 += __shfl_xor(a0, sh); a1 += __shfl_xor(a1, sh);
        a2 += __shfl_xor(a2, sh); a3 += __shfl_xor(a3, sh);
    }
    if (grp == 0) {
        float4 rt = *reinterpret_cast<const float4*>(Y2 + ((size_t)n * 17 + 16) * 16 + c4 * 4);
        float4 bb = *reinterpret_cast<const float4*>(b2 + c4 * 4);
        float4 o;
        o.x = 1.0f / (1.0f + expf(-(a0 + rt.x + bb.x)));
        o.y = 1.0f / (1.0f + expf(-(a1 + rt.y + bb.y)));
        o.z = 1.0f / (1.0f + expf(-(a2 + rt.z + bb.z)));
        o.w = 1.0f / (1.0f + expf(-(a3 + rt.w + bb.w)));
        *reinterpret_cast<float4*>(out + (size_t)n * NC + c4 * 4) = o;
    }
}

extern "C" void kernel_launch(void* const* d_in, const int* in_sizes, int n_in,
                              void* d_out, int out_size, void* d_ws, size_t ws_size,
                              hipStream_t stream) {
    const float* emb   = (const float*)d_in[0];
    const float* W1    = (const float*)d_in[1];
    const float* root1 = (const float*)d_in[2];
    const float* b1    = (const float*)d_in[3];
    const float* W2    = (const float*)d_in[4];
    const float* root2 = (const float*)d_in[5];
    const float* b2    = (const float*)d_in[6];
    const int*   ei    = (const int*)d_in[7];    // [2, NE]: src then dst
    const int*   et    = (const int*)d_in[8];
    float* out = (float*)d_out;

    char* ws = (char*)d_ws;
    // ws layout (bytes), total 132,313,344:
    //   cur4:    0          .. +800,000       (4x50000 i32)
    //   Bt1:     800,000    .. +278,528       (1088x128 f16)
    //   Bt2:     1,078,528  .. +34,816        (272x64 f16)
    //   packed4: 1,113,344  .. +16,000,000    (4x50000x20 u32)
    //   X1h:     17,113,344 .. +6,400,000     (50000x64 f16)
    //   Y1/Y2:   23,513,344 .. +108,800,000   (Y1 f16 [50000][1088]; Y2 f32 aliased)
    int*      cur4    = (int*)(ws + 0);
    f16*      Bt1     = (f16*)(ws + 800000);
    f16*      Bt2     = (f16*)(ws + 1078528);
    unsigned* packed4 = (unsigned*)(ws + 1113344);
    f16*      X1h     = (f16*)(ws + 17113344);
    f16*      Y1      = (f16*)(ws + 23513344);
    float*    Y2      = (float*)(ws + 23513344);   // aliases Y1 (dead after agg1f)

    hipMemsetAsync(cur4, 0, 800000, stream);

    k_bb<<<613, 256, 0, stream>>>(W1, root1, W2, root2, Bt1, Bt2);
    k_scat<<<(NE + 255) / 256, 256, 0, stream>>>(ei, et, cur4, packed4);

    dim3 g1((J1 + 127) / 128, (N_NODES + 127) / 128);   // 9 x 391
    k_gemm1<<<g1, 512, 0, stream>>>(emb, Bt1, Y1);

    k_agg1f<<<(N_NODES * 64) / 256, 256, 0, stream>>>(cur4, packed4, Y1, b1, X1h);

    dim3 g2((J2 + 127) / 128, (N_NODES + 127) / 128);   // 3 x 391
    k_mfma<HID, float><<<g2, 512, 0, stream>>>(X1h, Bt2, Y2, N_NODES, J2);

    k_agg2f<<<(N_NODES * 64) / 256, 256, 0, stream>>>(cur4, packed4, Y2, b2, out);
}

// Round 10
// 155.227 us; speedup vs baseline: 1.3775x; 1.3775x over previous
//
#include <hip/hip_runtime.h>
#include <hip/hip_fp16.h>

#define N_NODES 50000
#define EMB 128
#define HID 64
#define NR 16
#define NC 16
#define NE 800000
#define J1 (NR*HID + HID)   /* 1088 = 17*64 */
#define J2 (NR*NC + NC)     /* 272  = 17*16 */
#define CAP 64              /* bucket capacity (deg~Poisson(16)) */

typedef _Float16 f16;
typedef __attribute__((ext_vector_type(8))) _Float16 f16x8;
typedef __attribute__((ext_vector_type(4))) _Float16 f16x4;
typedef __attribute__((ext_vector_type(4))) float f32x4;

// ---- fused pre-pass: [cast emb->f16 | build Bt1/Bt2] -----------------------
#define PRE_CAST_BLK 6250              /* 1,600,000 f16x4 groups */
#define PRE_BB_BLK 613
__global__ __launch_bounds__(256)
void k_pre(const float* __restrict__ emb, const float* __restrict__ W1,
           const float* __restrict__ root1, const float* __restrict__ W2,
           const float* __restrict__ root2, f16* __restrict__ embh,
           f16* __restrict__ Bt1, f16* __restrict__ Bt2) {
    int bx = blockIdx.x, tid = threadIdx.x;
    if (bx < PRE_CAST_BLK) {
        int i = bx * 256 + tid;
        if (i < N_NODES * EMB / 4) {
            float4 v = reinterpret_cast<const float4*>(emb)[i];
            f16x4 r = {(f16)v.x, (f16)v.y, (f16)v.z, (f16)v.w};
            reinterpret_cast<f16x4*>(embh)[i] = r;
        }
    } else {
        int idx = (bx - PRE_CAST_BLK) * 256 + tid;
        const int total1 = J1 * EMB;   // 139264
        const int total2 = J2 * HID;   // 17408
        if (idx < total1) {
            int j = idx / EMB, i = idx % EMB;
            float v = (j < NR*HID) ? W1[((size_t)(j >> 6) * EMB + i) * HID + (j & 63)]
                                   : root1[i * HID + (j - NR*HID)];
            Bt1[idx] = (f16)v;
        } else if (idx < total1 + total2) {
            int t = idx - total1;
            int j = t / HID, i = t % HID;
            float v = (j < NR*NC) ? W2[((size_t)(j >> 4) * HID + i) * NC + (j & 15)]
                                  : root2[i * NC + (j - NR*NC)];
            Bt2[t] = (f16)v;
        }
    }
}

// ---- hybrid: GEMM1 (Y1 = embh @ Bt1^T) interleaved with edge scatter -------
// 13-block groups: r<9 -> gemm tile; r>=9 -> scatter (2048 edges/group).
// Bijective XCD swizzle (m204): all 13 blocks of a group land on ONE XCD, so
// the shared A row-block is fetched into exactly one XCD L2 (not 9).
#define NWG (391 * 13)      /* 5083 */
__global__ __launch_bounds__(512)
void k_g1s(const f16* __restrict__ A, const f16* __restrict__ Bt,
           f16* __restrict__ C, const int* __restrict__ ei,
           const int* __restrict__ et, int* __restrict__ cur,
           unsigned* __restrict__ packed) {
    constexpr int K = EMB, KP = K + 8;
    __shared__ f16 As[128 * KP];
    __shared__ f16 Bs[128 * KP];
    int wg = blockIdx.x;
    constexpr int qq = NWG / 8, rm = NWG % 8;    // 635, 3
    int xcd = wg & 7, slot = wg >> 3;
    int vg = (xcd < rm) ? xcd * (qq + 1) + slot
                        : rm * (qq + 1) + (xcd - rm) * qq + slot;
    int g13 = vg / 13, r = vg % 13;
    int tid = threadIdx.x;

    if (r >= 9) {                       // ---- scatter path ----
        int e = (g13 * 4 + (r - 9)) * 512 + tid;
        if (e < NE) {
            int s = ei[e], d = ei[NE + e], t = et[e];
            int pos = atomicAdd(&cur[d], 1);
            if (pos < CAP)
                packed[(size_t)d * CAP + pos] = (unsigned)(s * 17 + t);
        }
        return;
    }
    // ---- gemm path: N=N_NODES rows, J=J1 cols ----
    int m0 = g13 * 128, n0 = r * 128;
    constexpr int V = K / 8;
    for (int idx = tid; idx < 128 * V; idx += 512) {
        int rr = idx / V, c = idx % V;
        f16x8 va = {}, vb = {};
        if (m0 + rr < N_NODES) va = *reinterpret_cast<const f16x8*>(A + (size_t)(m0 + rr) * K + c * 8);
        if (n0 + rr < J1)      vb = *reinterpret_cast<const f16x8*>(Bt + (size_t)(n0 + rr) * K + c * 8);
        *reinterpret_cast<f16x8*>(&As[rr * KP + c * 8]) = va;
        *reinterpret_cast<f16x8*>(&Bs[rr * KP + c * 8]) = vb;
    }
    __syncthreads();

    int w = tid >> 6, lane = tid & 63;
    int wr = (w >> 2) * 64, wc = (w & 3) * 32;
    int lr = lane & 15, lk = (lane >> 4) * 8;

    f32x4 acc[4][2];
#pragma unroll
    for (int mm = 0; mm < 4; mm++)
#pragma unroll
        for (int nn = 0; nn < 2; nn++) acc[mm][nn] = (f32x4){0.f, 0.f, 0.f, 0.f};

#pragma unroll
    for (int k0 = 0; k0 < K; k0 += 32) {
        f16x8 a[4], b[2];
#pragma unroll
        for (int mm = 0; mm < 4; mm++)
            a[mm] = *reinterpret_cast<const f16x8*>(&As[(wr + mm*16 + lr) * KP + k0 + lk]);
#pragma unroll
        for (int nn = 0; nn < 2; nn++)
            b[nn] = *reinterpret_cast<const f16x8*>(&Bs[(wc + nn*16 + lr) * KP + k0 + lk]);
#pragma unroll
        for (int mm = 0; mm < 4; mm++)
#pragma unroll
            for (int nn = 0; nn < 2; nn++)
                acc[mm][nn] = __builtin_amdgcn_mfma_f32_16x16x32_f16(a[mm], b[nn], acc[mm][nn], 0, 0, 0);
    }

    int g = lane >> 4;
#pragma unroll
    for (int mm = 0; mm < 4; mm++)
#pragma unroll
        for (int nn = 0; nn < 2; nn++) {
            int col = n0 + wc + nn*16 + lr;
            if (col < J1) {
#pragma unroll
                for (int q = 0; q < 4; q++) {
                    int row = m0 + wr + mm*16 + g*4 + q;
                    if (row < N_NODES) C[(size_t)row * J1 + col] = (f16)acc[mm][nn][q];
                }
            }
        }
}

// ---- MFMA GEMM for layer 2 -------------------------------------------------
template<int K, typename OutT>
__global__ __launch_bounds__(512)
void k_mfma(const f16* __restrict__ A, const f16* __restrict__ Bt,
            OutT* __restrict__ C, int N, int J) {
    constexpr int KP = K + 8;
    __shared__ f16 As[128 * KP];
    __shared__ f16 Bs[128 * KP];
    int tid = threadIdx.x;
    int m0 = blockIdx.y * 128, n0 = blockIdx.x * 128;

    constexpr int V = K / 8;
    for (int idx = tid; idx < 128 * V; idx += 512) {
        int r = idx / V, c = idx % V;
        f16x8 va = {}, vb = {};
        if (m0 + r < N) va = *reinterpret_cast<const f16x8*>(A + (size_t)(m0 + r) * K + c * 8);
        if (n0 + r < J) vb = *reinterpret_cast<const f16x8*>(Bt + (size_t)(n0 + r) * K + c * 8);
        *reinterpret_cast<f16x8*>(&As[r * KP + c * 8]) = va;
        *reinterpret_cast<f16x8*>(&Bs[r * KP + c * 8]) = vb;
    }
    __syncthreads();

    int w = tid >> 6, lane = tid & 63;
    int wr = (w >> 2) * 64, wc = (w & 3) * 32;
    int lr = lane & 15, lk = (lane >> 4) * 8;

    f32x4 acc[4][2];
#pragma unroll
    for (int mm = 0; mm < 4; mm++)
#pragma unroll
        for (int nn = 0; nn < 2; nn++) acc[mm][nn] = (f32x4){0.f, 0.f, 0.f, 0.f};

#pragma unroll
    for (int k0 = 0; k0 < K; k0 += 32) {
        f16x8 a[4], b[2];
#pragma unroll
        for (int mm = 0; mm < 4; mm++)
            a[mm] = *reinterpret_cast<const f16x8*>(&As[(wr + mm*16 + lr) * KP + k0 + lk]);
#pragma unroll
        for (int nn = 0; nn < 2; nn++)
            b[nn] = *reinterpret_cast<const f16x8*>(&Bs[(wc + nn*16 + lr) * KP + k0 + lk]);
#pragma unroll
        for (int mm = 0; mm < 4; mm++)
#pragma unroll
            for (int nn = 0; nn < 2; nn++)
                acc[mm][nn] = __builtin_amdgcn_mfma_f32_16x16x32_f16(a[mm], b[nn], acc[mm][nn], 0, 0, 0);
    }

    int g = lane >> 4;
#pragma unroll
    for (int mm = 0; mm < 4; mm++)
#pragma unroll
        for (int nn = 0; nn < 2; nn++) {
            int col = n0 + wc + nn*16 + lr;
            if (col < J) {
#pragma unroll
                for (int q = 0; q < 4; q++) {
                    int row = m0 + wr + mm*16 + g*4 + q;
                    if (row < N) C[(size_t)row * J + col] = (OutT)acc[mm][nn][q];
                }
            }
        }
}

// ---- fused layer-1 aggregation + finalize ----------------------------------
// wave/node; 4 edge-groups x 16 channel-quads; f16x4 loads; ballot counts.
__global__ __launch_bounds__(256)
void k_agg1f(const int* __restrict__ cur, const unsigned* __restrict__ packed,
             const f16* __restrict__ Y1, const float* __restrict__ b1,
             f16* __restrict__ X1h) {
    int n = (blockIdx.x * 256 + threadIdx.x) >> 6;
    if (n >= N_NODES) return;
    int lane = threadIdx.x & 63;
    int deg = cur[n]; if (deg > CAP) deg = CAP;
    unsigned my = packed[(size_t)n * CAP + lane];   // stale for lane>=deg, masked
    int tp = (int)(my % 17u);                       // 0..16 always
    float wreg = 0.f;
#pragma unroll
    for (int r = 0; r < 16; r++) {
        unsigned long long b = __ballot(lane < deg && tp == r);
        if (lane == r) wreg = 1.0f / fmaxf((float)__popcll(b), 1.0f);
    }
    float w_my = __shfl(wreg, tp);                  // my edge's mean weight
    int c4 = lane & 15, grp = lane >> 4;
    const f16* Yb = Y1 + c4 * 4;
    float a0 = 0.f, a1 = 0.f, a2 = 0.f, a3 = 0.f;
    for (int i = 0; i < deg; i += 4) {              // wave-uniform bound
        int idx = i + grp;                          // <= 63 always
        unsigned en = __shfl(my, idx);              // all lanes active
        float we = __shfl(w_my, idx);
        if (idx < deg) {
            f16x4 v = *reinterpret_cast<const f16x4*>(Yb + ((size_t)en << 6));
            a0 += we * (float)v[0]; a1 += we * (float)v[1];
            a2 += we * (float)v[2]; a3 += we * (float)v[3];
        }
    }
    a0 += __shfl_xor(a0, 16); a0 += __shfl_xor(a0, 32);
    a1 += __shfl_xor(a1, 16); a1 += __shfl_xor(a1, 32);
    a2 += __shfl_xor(a2, 16); a2 += __shfl_xor(a2, 32);
    a3 += __shfl_xor(a3, 16); a3 += __shfl_xor(a3, 32);
    if (grp == 0) {
        f16x4 rt = *reinterpret_cast<const f16x4*>(Y1 + ((size_t)n * 17 + 16) * 64 + c4 * 4);
        float4 bb = *reinterpret_cast<const float4*>(b1 + c4 * 4);
        f16x4 o = {(f16)fmaxf(a0 + (float)rt[0] + bb.x, 0.f),
                   (f16)fmaxf(a1 + (float)rt[1] + bb.y, 0.f),
                   (f16)fmaxf(a2 + (float)rt[2] + bb.z, 0.f),
                   (f16)fmaxf(a3 + (float)rt[3] + bb.w, 0.f)};
        *reinterpret_cast<f16x4*>(X1h + (size_t)n * HID + c4 * 4) = o;
    }
}

// ---- fused layer-2 aggregation + finalize ----------------------------------
// wave/node; 16 edge-groups x 4 channel-quads; float4 loads (Y2 f32).
__global__ __launch_bounds__(256)
void k_agg2f(const int* __restrict__ cur, const unsigned* __restrict__ packed,
             const float* __restrict__ Y2, const float* __restrict__ b2,
             float* __restrict__ out) {
    int n = (blockIdx.x * 256 + threadIdx.x) >> 6;
    if (n >= N_NODES) return;
    int lane = threadIdx.x & 63;
    int deg = cur[n]; if (deg > CAP) deg = CAP;
    unsigned my = packed[(size_t)n * CAP + lane];
    int tp = (int)(my % 17u);
    float wreg = 0.f;
#pragma unroll
    for (int r = 0; r < 16; r++) {
        unsigned long long b = __ballot(lane < deg && tp == r);
        if (lane == r) wreg = 1.0f / fmaxf((float)__popcll(b), 1.0f);
    }
    float w_my = __shfl(wreg, tp);
    int c4 = lane & 3, grp = lane >> 2;             // 16 groups x 4 quads
    const float* Yb = Y2 + c4 * 4;
    float a0 = 0.f, a1 = 0.f, a2 = 0.f, a3 = 0.f;
    for (int i = 0; i < deg; i += 16) {             // usually 1-2 iterations
        int idx = i + grp;                          // <= 63 always (i<=48,grp<=15)
        unsigned en = __shfl(my, idx);
        float we = __shfl(w_my, idx);
        if (idx < deg) {
            float4 v = *reinterpret_cast<const float4*>(Yb + ((size_t)en << 4));
            a0 += we * v.x; a1 += we * v.y; a2 += we * v.z; a3 += we * v.w;
        }
    }
#pragma unroll
    for (int sh = 4; sh <= 32; sh <<= 1) {
        a0 += __shfl_xor(a0, sh); a1 += __shfl_xor(a1, sh);
        a2 += __shfl_xor(a2, sh); a3 += __shfl_xor(a3, sh);
    }
    if (grp == 0) {                                 // lanes 0..3
        float4 rt = *reinterpret_cast<const float4*>(Y2 + ((size_t)n * 17 + 16) * 16 + c4 * 4);
        float4 bb = *reinterpret_cast<const float4*>(b2 + c4 * 4);
        float4 o;
        o.x = 1.0f / (1.0f + expf(-(a0 + rt.x + bb.x)));
        o.y = 1.0f / (1.0f + expf(-(a1 + rt.y + bb.y)));
        o.z = 1.0f / (1.0f + expf(-(a2 + rt.z + bb.z)));
        o.w = 1.0f / (1.0f + expf(-(a3 + rt.w + bb.w)));
        *reinterpret_cast<float4*>(out + (size_t)n * NC + c4 * 4) = o;
    }
}

extern "C" void kernel_launch(void* const* d_in, const int* in_sizes, int n_in,
                              void* d_out, int out_size, void* d_ws, size_t ws_size,
                              hipStream_t stream) {
    const float* emb   = (const float*)d_in[0];
    const float* W1    = (const float*)d_in[1];
    const float* root1 = (const float*)d_in[2];
    const float* b1    = (const float*)d_in[3];
    const float* W2    = (const float*)d_in[4];
    const float* root2 = (const float*)d_in[5];
    const float* b2    = (const float*)d_in[6];
    const int*   ei    = (const int*)d_in[7];    // [2, NE]: src then dst
    const int*   et    = (const int*)d_in[8];
    float* out = (float*)d_out;

    char* ws = (char*)d_ws;
    // ws layout (bytes), total 134,913,344 (r6 layout):
    //   cur:      0          .. +200,000      (50000 i32)
    //   Bt1:      200,000    .. +278,528      (1088x128 f16)
    //   Bt2:      478,528    .. +34,816       (272x64 f16)
    //   packed:   513,344    .. +12,800,000   (50000x64 u32 buckets)
    //   embh/X1h: 13,313,344 .. +12,800,000   (embh dies at gemm1; X1h aliases)
    //   Y1/Y2:    26,113,344 .. +108,800,000  (Y1 f16 [50000][1088]; Y2 f32 [50000][272])
    int*      cur    = (int*)(ws + 0);
    f16*      Bt1    = (f16*)(ws + 200000);
    f16*      Bt2    = (f16*)(ws + 478528);
    unsigned* packed = (unsigned*)(ws + 513344);
    f16*      embh   = (f16*)(ws + 13313344);
    f16*      X1h    = (f16*)(ws + 13313344);    // aliases embh (disjoint lifetime)
    f16*      Y1     = (f16*)(ws + 26113344);
    float*    Y2     = (float*)(ws + 26113344);  // aliases Y1 (dead after agg1f)

    hipMemsetAsync(cur, 0, 200000, stream);

    // pre: cast(6250) + build_B(613) = 6863 blocks
    k_pre<<<PRE_CAST_BLK + PRE_BB_BLK, 256, 0, stream>>>(
        emb, W1, root1, W2, root2, embh, Bt1, Bt2);

    // hybrid gemm1+scatter, XCD-swizzled: 391 groups x 13 = 5083 blocks
    k_g1s<<<NWG, 512, 0, stream>>>(embh, Bt1, Y1, ei, et, cur, packed);

    k_agg1f<<<(N_NODES * 64 + 255) / 256, 256, 0, stream>>>(cur, packed, Y1, b1, X1h);

    dim3 g2((J2 + 127) / 128, (N_NODES + 127) / 128);   // 3 x 391
    k_mfma<HID, float><<<g2, 512, 0, stream>>>(X1h, Bt2, Y2, N_NODES, J2);

    k_agg2f<<<(N_NODES * 64 + 255) / 256, 256, 0, stream>>>(cur, packed, Y2, b2, out);
}